// Round 1
// baseline (327.664 us; speedup 1.0000x reference)
//
#include <hip/hip_runtime.h>
#include <math.h>
#include <float.h>

#define H 128
#define NCLS 10

// ---------------- K0: zero cnt[] + sort breakpoints (block nbN) ----------------
__global__ void k0_init_sort(int* __restrict__ cnt, int N,
                             const float* __restrict__ W1, const float* __restrict__ b1,
                             float* __restrict__ sortedt, int* __restrict__ rankarr,
                             int nZeroBlocks) {
  if ((int)blockIdx.x < nZeroBlocks) {
    int idx = blockIdx.x * 256 + threadIdx.x;
    if (idx < N) cnt[idx] = 0;
  } else {
    __shared__ float t_s[H];
    int j = threadIdx.x;
    if (j < H) {
      float w = W1[j];
      float t = (w != 0.0f) ? (-b1[j] / w) : INFINITY;
      t_s[j] = t;
    }
    __syncthreads();
    if (j < H) {
      float tj = t_s[j];
      int r = 0;
      for (int i = 0; i < H; ++i) {
        float ti = t_s[i];
        r += (ti < tj || (ti == tj && i < j)) ? 1 : 0;
      }
      sortedt[r] = tj;
      rankarr[j] = r;
    }
  }
}

// ---------------- K1: in-degree count ----------------
__global__ void k1_count(const int* __restrict__ ei, int E, int* __restrict__ cnt) {
  int e = blockIdx.x * 256 + threadIdx.x;
  if (e < E) atomicAdd(&cnt[ei[E + e]], 1);
}

// ---------------- K2: per-block scan of cnt + piecewise A/B tables ----------------
__global__ void k2_scan_tables(const int* __restrict__ cnt, int N,
                               int* __restrict__ rowptr, int* __restrict__ bsum,
                               int nScanBlocks,
                               const float* __restrict__ W1, const float* __restrict__ b1,
                               const float* __restrict__ W2,
                               const int* __restrict__ rankarr,
                               float* __restrict__ Atab, float* __restrict__ Btab) {
  int b = blockIdx.x;
  if (b < nScanBlocks) {
    __shared__ int arr[256];
    int t = threadIdx.x;
    int idx = b * 256 + t;
    int v = (idx < N) ? cnt[idx] : 0;
    arr[t] = v;
    __syncthreads();
    for (int off = 1; off < 256; off <<= 1) {
      int add = (t >= off) ? arr[t - off] : 0;
      __syncthreads();
      arr[t] += add;
      __syncthreads();
    }
    if (idx < N) rowptr[idx] = arr[t] - v;   // exclusive within block
    if (t == 255) bsum[b] = arr[255];
  } else {
    int s = b - nScanBlocks;                 // segment 0..128
    __shared__ float w_s[H], b_s[H];
    __shared__ int r_s[H];
    int t = threadIdx.x;
    if (t < H) { w_s[t] = W1[t]; b_s[t] = b1[t]; r_s[t] = rankarr[t]; }
    __syncthreads();
    if (t < H) {
      float A = 0.f, B = 0.f;
      for (int j = 0; j < H; ++j) {
        float w = w_s[j];
        bool active = (w > 0.f && r_s[j] < s) || (w < 0.f && r_s[j] >= s) ||
                      (w == 0.f && b_s[j] > 0.f);
        float w2 = W2[j * H + t];
        if (active) { A = fmaf(w, w2, A); B = fmaf(b_s[j], w2, B); }
      }
      Atab[s * H + t] = A;
      Btab[s * H + t] = B;
    }
  }
}

// ---------------- K3: scan of block sums ----------------
__global__ void k3_scan2(const int* __restrict__ bsum, int* __restrict__ boffs,
                         int nScanBlocks) {
  __shared__ int arr[256];
  int t = threadIdx.x;
  int v = (t < nScanBlocks) ? bsum[t] : 0;
  arr[t] = v;
  __syncthreads();
  for (int off = 1; off < 256; off <<= 1) {
    int add = (t >= off) ? arr[t - off] : 0;
    __syncthreads();
    arr[t] += add;
    __syncthreads();
  }
  boffs[t] = arr[t] - v;                      // exclusive
}

// ---------------- K4: finalize rowptr/cursor, dis, ux, graph starts ----------------
__global__ void k4_finalize(int* __restrict__ rowptr, const int* __restrict__ boffs,
                            int* __restrict__ cursor, const int* __restrict__ cnt,
                            const float* __restrict__ x, float* __restrict__ dis,
                            float* __restrict__ ux, const int* __restrict__ batch,
                            int* __restrict__ gstart, int N, int E, int G) {
  int idx = blockIdx.x * 256 + threadIdx.x;
  if (idx < N) {
    int r = rowptr[idx] + boffs[blockIdx.x];
    rowptr[idx] = r;
    cursor[idx] = r;
    float d = rsqrtf((float)(cnt[idx] + 1));   // +1 self loop, deg >= 1 always
    dis[idx] = d;
    ux[idx] = d * x[idx];
    int bi = batch[idx];
    if (idx == 0) { gstart[0] = 0; rowptr[N] = E; gstart[G] = N; }
    else if (batch[idx - 1] != bi) gstart[bi] = idx;
  }
}

// ---------------- K5: fill CSR ----------------
__global__ void k5_fill(const int* __restrict__ ei, int E,
                        int* __restrict__ cursor, int* __restrict__ csr) {
  int e = blockIdx.x * 256 + threadIdx.x;
  if (e < E) {
    int d = ei[E + e];
    int pos = atomicAdd(&cursor[d], 1);
    csr[pos] = ei[e];
  }
}

// ---------------- K7: per-node scalar s1 gather + piecewise eval -> u[n,0:128] ----
__global__ void k7_ueval(const int* __restrict__ rowptr, const int* __restrict__ csr,
                         const float* __restrict__ dis, const float* __restrict__ ux,
                         const float* __restrict__ sortedt,
                         const float* __restrict__ Atab, const float* __restrict__ Btab,
                         float* __restrict__ u, int N) {
  __shared__ float t_s[H];
  if (threadIdx.x < H) t_s[threadIdx.x] = sortedt[threadIdx.x];
  __syncthreads();
  int tid = blockIdx.x * 256 + threadIdx.x;
  int n = tid >> 5;            // 32 lanes per node (4 channels each)
  int sub = tid & 31;
  if (n >= N) return;
  int r0 = rowptr[n], r1 = rowptr[n + 1];
  float s = ux[n];             // self loop term
  for (int i = r0; i < r1; ++i) s += ux[csr[i]];
  float d = dis[n];
  float a = d * s;             // the scalar s1[n]
  // lower_bound: seg = #{sorted breakpoints < a}
  int lo = 0, hi = H;
  while (lo < hi) { int mid = (lo + hi) >> 1; if (t_s[mid] < a) lo = mid + 1; else hi = mid; }
  int seg = lo;
  int k0 = sub * 4;
  float4 A4 = *(const float4*)&Atab[seg * H + k0];
  float4 B4 = *(const float4*)&Btab[seg * H + k0];
  float4 r;
  r.x = d * fmaf(A4.x, a, B4.x);
  r.y = d * fmaf(A4.y, a, B4.y);
  r.z = d * fmaf(A4.z, a, B4.z);
  r.w = d * fmaf(A4.w, a, B4.w);
  *(float4*)&u[(size_t)n * H + k0] = r;
}

// ---------------- K8: aggregate + relu + pool + classifier + softmax -------------
__global__ __launch_bounds__(1024)
void k8_agg_pool(const int* __restrict__ rowptr, const int* __restrict__ csr,
                 const float* __restrict__ dis, const float* __restrict__ u,
                 const float* __restrict__ b2, const int* __restrict__ gstart,
                 const float* __restrict__ Wout, const float* __restrict__ bout,
                 float* __restrict__ out) {
  int g = blockIdx.x;
  int s0 = gstart[g], s1e = gstart[g + 1];
  int wave = threadIdx.x >> 6;        // 0..15
  int lane = threadIdx.x & 63;
  int k0 = lane * 2;
  float2 b2v = *(const float2*)&b2[k0];
  float mxa = -FLT_MAX, mxb = -FLT_MAX, sma = 0.f, smb = 0.f;
  for (int d = s0 + wave; d < s1e; d += 16) {
    int r0 = rowptr[d], r1 = rowptr[d + 1];
    float2 acc = *(const float2*)&u[(size_t)d * H + k0];   // self loop
    for (int i = r0; i < r1; ++i) {
      int sN = csr[i];
      float2 v = *(const float2*)&u[(size_t)sN * H + k0];
      acc.x += v.x; acc.y += v.y;
    }
    float dd = dis[d];
    float ha = fmaxf(fmaf(dd, acc.x, b2v.x), 0.f);
    float hb = fmaxf(fmaf(dd, acc.y, b2v.y), 0.f);
    mxa = fmaxf(mxa, ha); mxb = fmaxf(mxb, hb);
    sma += ha; smb += hb;
  }
  __shared__ float lmx[16 * H];
  __shared__ float lsm[16 * H];
  lmx[wave * H + k0] = mxa; lmx[wave * H + k0 + 1] = mxb;
  lsm[wave * H + k0] = sma; lsm[wave * H + k0 + 1] = smb;
  __syncthreads();
  __shared__ float pooled[2 * H];
  int t = threadIdx.x;
  if (t < H) {
    float m = -FLT_MAX, sm = 0.f;
    for (int w = 0; w < 16; ++w) { m = fmaxf(m, lmx[w * H + t]); sm += lsm[w * H + t]; }
    float cntg = (float)(s1e - s0);
    pooled[t] = m;
    pooled[H + t] = sm / fmaxf(cntg, 1.0f);
  }
  __syncthreads();
  __shared__ float logits[NCLS];
  if (t < NCLS) {
    float acc = bout[t];
    for (int j = 0; j < 2 * H; ++j) acc = fmaf(pooled[j], Wout[j * NCLS + t], acc);
    logits[t] = acc;
  }
  __syncthreads();
  if (t == 0) {
    float m = logits[0];
    for (int c = 1; c < NCLS; ++c) m = fmaxf(m, logits[c]);
    float ssum = 0.f;
    float ex[NCLS];
    for (int c = 0; c < NCLS; ++c) { ex[c] = expf(logits[c] - m); ssum += ex[c]; }
    float inv = 1.0f / ssum;
    for (int c = 0; c < NCLS; ++c) out[g * NCLS + c] = ex[c] * inv;
  }
}

extern "C" void kernel_launch(void* const* d_in, const int* in_sizes, int n_in,
                              void* d_out, int out_size, void* d_ws, size_t ws_size,
                              hipStream_t stream) {
  const float* x    = (const float*)d_in[0];
  const int*   ei   = (const int*)d_in[1];
  const int*   batch= (const int*)d_in[2];
  const float* W1   = (const float*)d_in[3];
  const float* b1   = (const float*)d_in[4];
  const float* W2   = (const float*)d_in[5];
  const float* b2   = (const float*)d_in[6];
  const float* Wout = (const float*)d_in[7];
  const float* bout = (const float*)d_in[8];
  float* out = (float*)d_out;

  int N = in_sizes[0];          // 50000
  int E = in_sizes[1] / 2;      // 625000
  int G = out_size / NCLS;      // 256

  // workspace carve-up (256B aligned)
  char* ws = (char*)d_ws;
  size_t off = 0;
  auto alloc = [&](size_t bytes) {
    char* p = ws + off;
    off += (bytes + 255) & ~(size_t)255;
    return p;
  };
  int*   cnt     = (int*)alloc(sizeof(int) * N);
  int*   rowptr  = (int*)alloc(sizeof(int) * (N + 1));
  int*   cursor  = (int*)alloc(sizeof(int) * N);
  int*   csr     = (int*)alloc(sizeof(int) * E);
  int*   bsum    = (int*)alloc(sizeof(int) * 256);
  int*   boffs   = (int*)alloc(sizeof(int) * 256);
  float* dis     = (float*)alloc(sizeof(float) * N);
  float* ux      = (float*)alloc(sizeof(float) * N);
  float* sortedt = (float*)alloc(sizeof(float) * H);
  int*   rankarr = (int*)alloc(sizeof(int) * H);
  float* Atab    = (float*)alloc(sizeof(float) * (H + 1) * H);
  float* Btab    = (float*)alloc(sizeof(float) * (H + 1) * H);
  int*   gstart  = (int*)alloc(sizeof(int) * (G + 1));
  float* u       = (float*)alloc(sizeof(float) * (size_t)N * H);
  (void)ws_size; (void)n_in;

  int nbN = (N + 255) / 256;    // 196
  int nbE = (E + 255) / 256;

  k0_init_sort<<<nbN + 1, 256, 0, stream>>>(cnt, N, W1, b1, sortedt, rankarr, nbN);
  k1_count<<<nbE, 256, 0, stream>>>(ei, E, cnt);
  k2_scan_tables<<<nbN + H + 1, 256, 0, stream>>>(cnt, N, rowptr, bsum, nbN,
                                                  W1, b1, W2, rankarr, Atab, Btab);
  k3_scan2<<<1, 256, 0, stream>>>(bsum, boffs, nbN);
  k4_finalize<<<nbN, 256, 0, stream>>>(rowptr, boffs, cursor, cnt, x, dis, ux,
                                       batch, gstart, N, E, G);
  k5_fill<<<nbE, 256, 0, stream>>>(ei, E, cursor, csr);
  k7_ueval<<<(N * 32 + 255) / 256, 256, 0, stream>>>(rowptr, csr, dis, ux, sortedt,
                                                     Atab, Btab, u, N);
  k8_agg_pool<<<G, 1024, 0, stream>>>(rowptr, csr, dis, u, b2, gstart, Wout, bout, out);
}

// Round 2
// 277.544 us; speedup vs baseline: 1.1806x; 1.1806x over previous
//
#include <hip/hip_runtime.h>
#include <math.h>
#include <float.h>

#define H 128
#define NCLS 10

// ---------------- K0: zero cnt[] + sort breakpoints (block nbN) ----------------
__global__ void k0_init_sort(int* __restrict__ cnt, int N,
                             const float* __restrict__ W1, const float* __restrict__ b1,
                             float* __restrict__ sortedt, int* __restrict__ rankarr,
                             int nZeroBlocks) {
  if ((int)blockIdx.x < nZeroBlocks) {
    int idx = blockIdx.x * 256 + threadIdx.x;
    if (idx < N) cnt[idx] = 0;
  } else {
    __shared__ float t_s[H];
    int j = threadIdx.x;
    if (j < H) {
      float w = W1[j];
      float t = (w != 0.0f) ? (-b1[j] / w) : INFINITY;
      t_s[j] = t;
    }
    __syncthreads();
    if (j < H) {
      float tj = t_s[j];
      int r = 0;
      for (int i = 0; i < H; ++i) {
        float ti = t_s[i];
        r += (ti < tj || (ti == tj && i < j)) ? 1 : 0;
      }
      sortedt[r] = tj;
      rankarr[j] = r;
    }
  }
}

// ---------------- K1: in-degree count ----------------
__global__ void k1_count(const int* __restrict__ ei, int E, int* __restrict__ cnt) {
  int e = blockIdx.x * 256 + threadIdx.x;
  if (e < E) atomicAdd(&cnt[ei[E + e]], 1);
}

// ---------------- K2: per-block scan of cnt + piecewise A/B tables ----------------
__global__ void k2_scan_tables(const int* __restrict__ cnt, int N,
                               int* __restrict__ rowptr, int* __restrict__ bsum,
                               int nScanBlocks,
                               const float* __restrict__ W1, const float* __restrict__ b1,
                               const float* __restrict__ W2,
                               const int* __restrict__ rankarr,
                               float* __restrict__ Atab, float* __restrict__ Btab) {
  int b = blockIdx.x;
  if (b < nScanBlocks) {
    __shared__ int arr[256];
    int t = threadIdx.x;
    int idx = b * 256 + t;
    int v = (idx < N) ? cnt[idx] : 0;
    arr[t] = v;
    __syncthreads();
    for (int off = 1; off < 256; off <<= 1) {
      int add = (t >= off) ? arr[t - off] : 0;
      __syncthreads();
      arr[t] += add;
      __syncthreads();
    }
    if (idx < N) rowptr[idx] = arr[t] - v;   // exclusive within block
    if (t == 255) bsum[b] = arr[255];
  } else {
    int s = b - nScanBlocks;                 // segment 0..128
    __shared__ float w_s[H], b_s[H];
    __shared__ int r_s[H];
    int t = threadIdx.x;
    if (t < H) { w_s[t] = W1[t]; b_s[t] = b1[t]; r_s[t] = rankarr[t]; }
    __syncthreads();
    if (t < H) {
      float A = 0.f, B = 0.f;
      for (int j = 0; j < H; ++j) {
        float w = w_s[j];
        bool active = (w > 0.f && r_s[j] < s) || (w < 0.f && r_s[j] >= s) ||
                      (w == 0.f && b_s[j] > 0.f);
        float w2 = W2[j * H + t];
        if (active) { A = fmaf(w, w2, A); B = fmaf(b_s[j], w2, B); }
      }
      Atab[s * H + t] = A;
      Btab[s * H + t] = B;
    }
  }
}

// ---------------- K3: scan of block sums ----------------
__global__ void k3_scan2(const int* __restrict__ bsum, int* __restrict__ boffs,
                         int nScanBlocks) {
  __shared__ int arr[256];
  int t = threadIdx.x;
  int v = (t < nScanBlocks) ? bsum[t] : 0;
  arr[t] = v;
  __syncthreads();
  for (int off = 1; off < 256; off <<= 1) {
    int add = (t >= off) ? arr[t - off] : 0;
    __syncthreads();
    arr[t] += add;
    __syncthreads();
  }
  boffs[t] = arr[t] - v;                      // exclusive
}

// ---------------- K4: finalize rowptr/cursor, dis, ux, graph starts ----------------
__global__ void k4_finalize(int* __restrict__ rowptr, const int* __restrict__ boffs,
                            int* __restrict__ cursor, const int* __restrict__ cnt,
                            const float* __restrict__ x, float* __restrict__ dis,
                            float* __restrict__ ux, const int* __restrict__ batch,
                            int* __restrict__ gstart, int N, int E, int G) {
  int idx = blockIdx.x * 256 + threadIdx.x;
  if (idx < N) {
    int r = rowptr[idx] + boffs[blockIdx.x];
    rowptr[idx] = r;
    cursor[idx] = r;
    float d = rsqrtf((float)(cnt[idx] + 1));   // +1 self loop, deg >= 1 always
    dis[idx] = d;
    ux[idx] = d * x[idx];
    int bi = batch[idx];
    if (idx == 0) { gstart[0] = 0; rowptr[N] = E; gstart[G] = N; }
    else if (batch[idx - 1] != bi) gstart[bi] = idx;
  }
}

// ---------------- K5: fill CSR ----------------
__global__ void k5_fill(const int* __restrict__ ei, int E,
                        int* __restrict__ cursor, int* __restrict__ csr) {
  int e = blockIdx.x * 256 + threadIdx.x;
  if (e < E) {
    int d = ei[E + e];
    int pos = atomicAdd(&cursor[d], 1);
    csr[pos] = ei[e];
  }
}

// ---------------- K6: per-node scalar a, segment -> vaseg = {d*a, d, seg} --------
__global__ void k6_scalar(const int* __restrict__ rowptr, const int* __restrict__ csr,
                          const float* __restrict__ dis, const float* __restrict__ ux,
                          const float* __restrict__ sortedt,
                          float4* __restrict__ vaseg, int N) {
  __shared__ float t_s[H];
  if (threadIdx.x < H) t_s[threadIdx.x] = sortedt[threadIdx.x];
  __syncthreads();
  int wid = (blockIdx.x * 256 + threadIdx.x) >> 6;   // one wave per node
  int lane = threadIdx.x & 63;
  if (wid >= N) return;
  int r0 = rowptr[wid], r1 = rowptr[wid + 1];
  float s = 0.f;
  for (int i = r0 + lane; i < r1; i += 64) s += ux[csr[i]];
  #pragma unroll
  for (int off = 32; off > 0; off >>= 1) s += __shfl_down(s, off);
  s = __shfl(s, 0) + ux[wid];                        // + self loop
  float d = dis[wid];
  float a = d * s;
  int lo = 0, hi = H;
  while (lo < hi) { int mid = (lo + hi) >> 1; if (t_s[mid] < a) lo = mid + 1; else hi = mid; }
  if (lane == 0) vaseg[wid] = make_float4(d * a, d, __int_as_float(lo), 0.f);
}

// ---------------- K8a: aggregate via table combo + partial pool ------------------
__global__ __launch_bounds__(1024)
void k8a_agg(const int* __restrict__ rowptr, const int* __restrict__ csr,
             const float4* __restrict__ vaseg,
             const float* __restrict__ Atab, const float* __restrict__ Btab,
             const float* __restrict__ b2, const int* __restrict__ gstart,
             float* __restrict__ pmax, float* __restrict__ psum) {
  int g = blockIdx.x >> 1, half = blockIdx.x & 1;
  int gs = gstart[g], ge = gstart[g + 1];
  int mid = gs + ((ge - gs) >> 1);
  int s0 = half ? mid : gs;
  int s1e = half ? ge : mid;
  int wave = threadIdx.x >> 6;        // 0..15
  int lane = threadIdx.x & 63;
  int k0 = lane * 2;
  float2 b2v = *(const float2*)&b2[k0];
  float mxa = -FLT_MAX, mxb = -FLT_MAX, sma = 0.f, smb = 0.f;
  for (int d = s0 + wave; d < s1e; d += 16) {
    int r0 = rowptr[d], r1 = rowptr[d + 1];
    float4 pd = vaseg[d];
    int segd = __float_as_int(pd.z);
    float2 Av = *(const float2*)&Atab[segd * H + k0];
    float2 Bv = *(const float2*)&Btab[segd * H + k0];
    float accx = pd.x * Av.x + pd.y * Bv.x;       // self-loop term
    float accy = pd.x * Av.y + pd.y * Bv.y;
    #pragma unroll 4
    for (int i = r0; i < r1; ++i) {
      int sN = csr[i];
      float4 ps = vaseg[sN];
      int seg = __float_as_int(ps.z);
      float2 A2 = *(const float2*)&Atab[seg * H + k0];
      float2 B2 = *(const float2*)&Btab[seg * H + k0];
      accx += ps.x * A2.x + ps.y * B2.x;
      accy += ps.x * A2.y + ps.y * B2.y;
    }
    float dd = pd.y;
    float ha = fmaxf(fmaf(dd, accx, b2v.x), 0.f);
    float hb = fmaxf(fmaf(dd, accy, b2v.y), 0.f);
    mxa = fmaxf(mxa, ha); mxb = fmaxf(mxb, hb);
    sma += ha; smb += hb;
  }
  __shared__ float lmx[16 * H];
  __shared__ float lsm[16 * H];
  lmx[wave * H + k0] = mxa; lmx[wave * H + k0 + 1] = mxb;
  lsm[wave * H + k0] = sma; lsm[wave * H + k0 + 1] = smb;
  __syncthreads();
  int t = threadIdx.x;
  if (t < H) {
    float m = -FLT_MAX, sm = 0.f;
    #pragma unroll
    for (int w = 0; w < 16; ++w) { m = fmaxf(m, lmx[w * H + t]); sm += lsm[w * H + t]; }
    pmax[(size_t)blockIdx.x * H + t] = m;
    psum[(size_t)blockIdx.x * H + t] = sm;
  }
}

// ---------------- K8b: combine halves + classifier + softmax ---------------------
__global__ void k8b_final(const float* __restrict__ pmax, const float* __restrict__ psum,
                          const int* __restrict__ gstart,
                          const float* __restrict__ Wout, const float* __restrict__ bout,
                          float* __restrict__ out) {
  int g = blockIdx.x;
  int t = threadIdx.x;
  __shared__ float pooled[2 * H];
  __shared__ float logits[NCLS];
  if (t < H) {
    float m = fmaxf(pmax[(size_t)(2 * g) * H + t], pmax[(size_t)(2 * g + 1) * H + t]);
    float sm = psum[(size_t)(2 * g) * H + t] + psum[(size_t)(2 * g + 1) * H + t];
    float cnt = (float)(gstart[g + 1] - gstart[g]);
    pooled[t] = m;
    pooled[H + t] = sm / fmaxf(cnt, 1.0f);
  }
  __syncthreads();
  if (t < NCLS) {
    float acc = bout[t];
    for (int j = 0; j < 2 * H; ++j) acc = fmaf(pooled[j], Wout[j * NCLS + t], acc);
    logits[t] = acc;
  }
  __syncthreads();
  if (t == 0) {
    float m = logits[0];
    for (int c = 1; c < NCLS; ++c) m = fmaxf(m, logits[c]);
    float ssum = 0.f;
    float ex[NCLS];
    for (int c = 0; c < NCLS; ++c) { ex[c] = expf(logits[c] - m); ssum += ex[c]; }
    float inv = 1.0f / ssum;
    for (int c = 0; c < NCLS; ++c) out[g * NCLS + c] = ex[c] * inv;
  }
}

extern "C" void kernel_launch(void* const* d_in, const int* in_sizes, int n_in,
                              void* d_out, int out_size, void* d_ws, size_t ws_size,
                              hipStream_t stream) {
  const float* x    = (const float*)d_in[0];
  const int*   ei   = (const int*)d_in[1];
  const int*   batch= (const int*)d_in[2];
  const float* W1   = (const float*)d_in[3];
  const float* b1   = (const float*)d_in[4];
  const float* W2   = (const float*)d_in[5];
  const float* b2   = (const float*)d_in[6];
  const float* Wout = (const float*)d_in[7];
  const float* bout = (const float*)d_in[8];
  float* out = (float*)d_out;

  int N = in_sizes[0];          // 50000
  int E = in_sizes[1] / 2;      // 625000
  int G = out_size / NCLS;      // 256

  // workspace carve-up (256B aligned)
  char* ws = (char*)d_ws;
  size_t off = 0;
  auto alloc = [&](size_t bytes) {
    char* p = ws + off;
    off += (bytes + 255) & ~(size_t)255;
    return p;
  };
  int*    cnt     = (int*)alloc(sizeof(int) * N);
  int*    rowptr  = (int*)alloc(sizeof(int) * (N + 1));
  int*    cursor  = (int*)alloc(sizeof(int) * N);
  int*    csr     = (int*)alloc(sizeof(int) * E);
  int*    bsum    = (int*)alloc(sizeof(int) * 256);
  int*    boffs   = (int*)alloc(sizeof(int) * 256);
  float*  dis     = (float*)alloc(sizeof(float) * N);
  float*  ux      = (float*)alloc(sizeof(float) * N);
  float*  sortedt = (float*)alloc(sizeof(float) * H);
  int*    rankarr = (int*)alloc(sizeof(int) * H);
  float*  Atab    = (float*)alloc(sizeof(float) * (H + 1) * H);
  float*  Btab    = (float*)alloc(sizeof(float) * (H + 1) * H);
  int*    gstart  = (int*)alloc(sizeof(int) * (G + 1));
  float4* vaseg   = (float4*)alloc(sizeof(float4) * N);
  float*  pmax    = (float*)alloc(sizeof(float) * 2 * G * H);
  float*  psum    = (float*)alloc(sizeof(float) * 2 * G * H);
  (void)ws_size; (void)n_in;

  int nbN = (N + 255) / 256;    // 196
  int nbE = (E + 255) / 256;

  k0_init_sort<<<nbN + 1, 256, 0, stream>>>(cnt, N, W1, b1, sortedt, rankarr, nbN);
  k1_count<<<nbE, 256, 0, stream>>>(ei, E, cnt);
  k2_scan_tables<<<nbN + H + 1, 256, 0, stream>>>(cnt, N, rowptr, bsum, nbN,
                                                  W1, b1, W2, rankarr, Atab, Btab);
  k3_scan2<<<1, 256, 0, stream>>>(bsum, boffs, nbN);
  k4_finalize<<<nbN, 256, 0, stream>>>(rowptr, boffs, cursor, cnt, x, dis, ux,
                                       batch, gstart, N, E, G);
  k5_fill<<<nbE, 256, 0, stream>>>(ei, E, cursor, csr);
  k6_scalar<<<(N * 64 + 255) / 256, 256, 0, stream>>>(rowptr, csr, dis, ux, sortedt,
                                                      vaseg, N);
  k8a_agg<<<2 * G, 1024, 0, stream>>>(rowptr, csr, vaseg, Atab, Btab, b2, gstart,
                                      pmax, psum);
  k8b_final<<<G, 256, 0, stream>>>(pmax, psum, gstart, Wout, bout, out);
}

// Round 3
// 240.625 us; speedup vs baseline: 1.3617x; 1.1534x over previous
//
#include <hip/hip_runtime.h>
#include <math.h>
#include <float.h>

#define H 128
#define NCLS 10
#define FXSCALE 1048576.0f
#define INV_FXSCALE (1.0f/1048576.0f)

// ---------------- KA: breakpoint sort + interleaved piecewise tables -------------
// 129 blocks (one per segment) x 128 threads; each block self-computes ranks.
__global__ void ka_tables(const float* __restrict__ W1, const float* __restrict__ b1,
                          const float* __restrict__ W2,
                          float* __restrict__ sortedt, float4* __restrict__ tab4) {
  __shared__ float tw[H], tb[H], tt[H];
  __shared__ int tr[H];
  __shared__ float As[H], Bs[H];
  int t = threadIdx.x;            // 0..127
  int s = blockIdx.x;             // 0..128
  float w = W1[t], b = b1[t];
  tw[t] = w; tb[t] = b;
  tt[t] = (w != 0.0f) ? (-b / w) : INFINITY;
  __syncthreads();
  float tj = tt[t];
  int r = 0;
  for (int i = 0; i < H; ++i) {
    float ti = tt[i];
    r += (ti < tj || (ti == tj && i < t)) ? 1 : 0;
  }
  tr[t] = r;
  if (s == 0) sortedt[r] = tj;
  __syncthreads();
  float A = 0.f, B = 0.f;
  for (int j = 0; j < H; ++j) {
    float wj = tw[j];
    bool active = (wj > 0.f && tr[j] < s) || (wj < 0.f && tr[j] >= s) ||
                  (wj == 0.f && tb[j] > 0.f);
    if (active) {
      float w2 = W2[j * H + t];
      A = fmaf(wj, w2, A);
      B = fmaf(tb[j], w2, B);
    }
  }
  As[t] = A; Bs[t] = B;
  __syncthreads();
  if (t < 64) {
    tab4[s * 64 + t] = make_float4(As[2 * t], As[2 * t + 1], Bs[2 * t], Bs[2 * t + 1]);
  }
}

// ---------------- KB: in-degree count, 8-way privatized --------------------------
__global__ void kb_count(const int* __restrict__ ei, int E, int N,
                         int* __restrict__ cnt8) {
  int e = blockIdx.x * 256 + threadIdx.x;
  if (e < E) {
    int dst = ei[E + e];
    atomicAdd(&cnt8[(blockIdx.x & 7) * N + dst], 1);
  }
}

// ---------------- KC: sum 8 copies + per-block scan ------------------------------
__global__ void kc_scan(const int* __restrict__ cnt8, int N,
                        int* __restrict__ cntT, int* __restrict__ rowptr,
                        int* __restrict__ bsum) {
  __shared__ int arr[256];
  int t = threadIdx.x;
  int idx = blockIdx.x * 256 + t;
  int v = 0;
  if (idx < N) {
    #pragma unroll
    for (int c = 0; c < 8; ++c) v += cnt8[c * N + idx];
    cntT[idx] = v;
  }
  arr[t] = v;
  __syncthreads();
  for (int off = 1; off < 256; off <<= 1) {
    int add = (t >= off) ? arr[t - off] : 0;
    __syncthreads();
    arr[t] += add;
    __syncthreads();
  }
  if (idx < N) rowptr[idx] = arr[t] - v;      // exclusive within block
  if (t == 255) bsum[blockIdx.x] = arr[255];
}

// ---------------- KD: redundant scan2 + rowptr/cursor8/dis/ux/gstart -------------
__global__ void kd_finalize(int* __restrict__ rowptr, const int* __restrict__ bsum,
                            const int* __restrict__ cntT, const int* __restrict__ cnt8,
                            int* __restrict__ cursor8,
                            const float* __restrict__ x, float* __restrict__ dis,
                            float* __restrict__ ux, const int* __restrict__ batch,
                            int* __restrict__ gstart, int N, int E, int G,
                            int nScanBlocks) {
  __shared__ int arr[256];
  __shared__ int vown;
  int t = threadIdx.x;
  int v = (t < nScanBlocks) ? bsum[t] : 0;
  arr[t] = v;
  if (t == (int)blockIdx.x) vown = v;
  __syncthreads();
  for (int off = 1; off < 256; off <<= 1) {
    int add = (t >= off) ? arr[t - off] : 0;
    __syncthreads();
    arr[t] += add;
    __syncthreads();
  }
  int boff = arr[blockIdx.x] - vown;          // exclusive block offset
  int idx = blockIdx.x * 256 + t;
  if (idx < N) {
    int r = rowptr[idx] + boff;
    rowptr[idx] = r;
    int running = r;
    #pragma unroll
    for (int c = 0; c < 8; ++c) {
      cursor8[c * N + idx] = running;
      running += cnt8[c * N + idx];
    }
    int deg = cntT[idx];
    float d = rsqrtf((float)(deg + 1));       // +1 self loop
    dis[idx] = d;
    ux[idx] = d * x[idx];
    int bi = batch[idx];
    if (idx == 0) { gstart[0] = 0; rowptr[N] = E; gstart[G] = N; }
    else if (batch[idx - 1] != bi) gstart[bi] = idx;
  }
}

// ---------------- KE: CSR fill + fixed-point s1 accumulation (privatized) --------
__global__ void ke_fill(const int* __restrict__ ei, int E, int N,
                        int* __restrict__ cursor8, int* __restrict__ s1i,
                        const float* __restrict__ ux, int* __restrict__ csr) {
  int e = blockIdx.x * 256 + threadIdx.x;
  if (e < E) {
    int c = blockIdx.x & 7;
    int src = ei[e];
    int dst = ei[E + e];
    int pos = atomicAdd(&cursor8[c * N + dst], 1);
    csr[pos] = src;
    int contrib = __float2int_rn(ux[src] * FXSCALE);
    atomicAdd(&s1i[c * N + dst], contrib);
  }
}

// ---------------- KF: elementwise vaseg = {d*a, d, seg} --------------------------
__global__ void kf_vaseg(const int* __restrict__ s1i, const float* __restrict__ ux,
                         const float* __restrict__ dis,
                         const float* __restrict__ sortedt,
                         float4* __restrict__ vaseg, int N) {
  __shared__ float t_s[H];
  if (threadIdx.x < H) t_s[threadIdx.x] = sortedt[threadIdx.x];
  __syncthreads();
  int idx = blockIdx.x * 256 + threadIdx.x;
  if (idx >= N) return;
  int acc = 0;
  #pragma unroll
  for (int c = 0; c < 8; ++c) acc += s1i[c * N + idx];
  float s = (float)acc * INV_FXSCALE + ux[idx];   // + self loop
  float d = dis[idx];
  float a = d * s;
  int lo = 0, hi = H;
  while (lo < hi) { int mid = (lo + hi) >> 1; if (t_s[mid] < a) lo = mid + 1; else hi = mid; }
  vaseg[idx] = make_float4(d * a, d, __int_as_float(lo), 0.f);
}

// ---------------- KG: parallel-gather aggregation + partial pool -----------------
__global__ __launch_bounds__(1024)
void kg_agg(const int* __restrict__ rowptr, const int* __restrict__ csr,
            const float4* __restrict__ vaseg, const float4* __restrict__ tab4,
            const float* __restrict__ b2, const int* __restrict__ gstart,
            float* __restrict__ pmax, float* __restrict__ psum) {
  __shared__ float4 stash[16][64];
  __shared__ float lmx[16 * H];
  __shared__ float lsm[16 * H];
  int g = blockIdx.x >> 1, half = blockIdx.x & 1;
  int gs = gstart[g], ge = gstart[g + 1];
  int mid = gs + ((ge - gs) >> 1);
  int s0 = half ? mid : gs;
  int s1e = half ? ge : mid;
  int wave = threadIdx.x >> 6;
  int lane = threadIdx.x & 63;
  int k0 = lane * 2;
  float2 b2v = *(const float2*)&b2[k0];
  float mxa = -FLT_MAX, mxb = -FLT_MAX, sma = 0.f, smb = 0.f;
  for (int d = s0 + wave; d < s1e; d += 16) {
    int r0 = rowptr[d], r1 = rowptr[d + 1];
    float4 pd = vaseg[d];
    int segd = __float_as_int(pd.z);
    float4 T = tab4[segd * 64 + lane];
    float accx = fmaf(pd.x, T.x, pd.y * T.z);      // self-loop term
    float accy = fmaf(pd.x, T.y, pd.y * T.w);
    for (int base = r0; base < r1; base += 64) {
      int m = min(64, r1 - base);
      if (lane < m) {
        int sN = csr[base + lane];
        stash[wave][lane] = vaseg[sN];             // parallel gather
      }
      __builtin_amdgcn_wave_barrier();
      __threadfence_block();                       // order LDS write -> read (wave-local)
      for (int j = 0; j < m; ++j) {
        float4 ps = stash[wave][j];                // broadcast read
        int seg = __float_as_int(ps.z);
        float4 Tj = tab4[seg * 64 + lane];
        accx = fmaf(ps.x, Tj.x, fmaf(ps.y, Tj.z, accx));
        accy = fmaf(ps.x, Tj.y, fmaf(ps.y, Tj.w, accy));
      }
      __builtin_amdgcn_wave_barrier();
    }
    float dd = pd.y;
    float ha = fmaxf(fmaf(dd, accx, b2v.x), 0.f);
    float hb = fmaxf(fmaf(dd, accy, b2v.y), 0.f);
    mxa = fmaxf(mxa, ha); mxb = fmaxf(mxb, hb);
    sma += ha; smb += hb;
  }
  lmx[wave * H + k0] = mxa; lmx[wave * H + k0 + 1] = mxb;
  lsm[wave * H + k0] = sma; lsm[wave * H + k0 + 1] = smb;
  __syncthreads();
  int t = threadIdx.x;
  if (t < H) {
    float m = -FLT_MAX, sm = 0.f;
    #pragma unroll
    for (int w = 0; w < 16; ++w) { m = fmaxf(m, lmx[w * H + t]); sm += lsm[w * H + t]; }
    pmax[(size_t)blockIdx.x * H + t] = m;
    psum[(size_t)blockIdx.x * H + t] = sm;
  }
}

// ---------------- KH: combine halves + classifier + softmax ----------------------
__global__ void kh_final(const float* __restrict__ pmax, const float* __restrict__ psum,
                         const int* __restrict__ gstart,
                         const float* __restrict__ Wout, const float* __restrict__ bout,
                         float* __restrict__ out) {
  int g = blockIdx.x;
  int t = threadIdx.x;
  __shared__ float pooled[2 * H];
  __shared__ float logits[NCLS];
  if (t < H) {
    float m = fmaxf(pmax[(size_t)(2 * g) * H + t], pmax[(size_t)(2 * g + 1) * H + t]);
    float sm = psum[(size_t)(2 * g) * H + t] + psum[(size_t)(2 * g + 1) * H + t];
    float cnt = (float)(gstart[g + 1] - gstart[g]);
    pooled[t] = m;
    pooled[H + t] = sm / fmaxf(cnt, 1.0f);
  }
  __syncthreads();
  if (t < NCLS) {
    float acc = bout[t];
    for (int j = 0; j < 2 * H; ++j) acc = fmaf(pooled[j], Wout[j * NCLS + t], acc);
    logits[t] = acc;
  }
  __syncthreads();
  if (t == 0) {
    float m = logits[0];
    for (int c = 1; c < NCLS; ++c) m = fmaxf(m, logits[c]);
    float ssum = 0.f;
    float ex[NCLS];
    for (int c = 0; c < NCLS; ++c) { ex[c] = expf(logits[c] - m); ssum += ex[c]; }
    float inv = 1.0f / ssum;
    for (int c = 0; c < NCLS; ++c) out[g * NCLS + c] = ex[c] * inv;
  }
}

extern "C" void kernel_launch(void* const* d_in, const int* in_sizes, int n_in,
                              void* d_out, int out_size, void* d_ws, size_t ws_size,
                              hipStream_t stream) {
  const float* x    = (const float*)d_in[0];
  const int*   ei   = (const int*)d_in[1];
  const int*   batch= (const int*)d_in[2];
  const float* W1   = (const float*)d_in[3];
  const float* b1   = (const float*)d_in[4];
  const float* W2   = (const float*)d_in[5];
  const float* b2   = (const float*)d_in[6];
  const float* Wout = (const float*)d_in[7];
  const float* bout = (const float*)d_in[8];
  float* out = (float*)d_out;

  int N = in_sizes[0];          // 50000
  int E = in_sizes[1] / 2;      // 625000
  int G = out_size / NCLS;      // 256

  char* ws = (char*)d_ws;
  size_t off = 0;
  auto alloc = [&](size_t bytes) {
    char* p = ws + off;
    off += (bytes + 255) & ~(size_t)255;
    return p;
  };
  int*    cnt8    = (int*)alloc(sizeof(int) * 8 * N);
  int*    s1i     = (int*)alloc(sizeof(int) * 8 * N);
  int*    rowptr  = (int*)alloc(sizeof(int) * (N + 1));
  int*    cntT    = (int*)alloc(sizeof(int) * N);
  int*    cursor8 = (int*)alloc(sizeof(int) * 8 * N);
  int*    csr     = (int*)alloc(sizeof(int) * E);
  int*    bsum    = (int*)alloc(sizeof(int) * 256);
  float*  dis     = (float*)alloc(sizeof(float) * N);
  float*  ux      = (float*)alloc(sizeof(float) * N);
  float*  sortedt = (float*)alloc(sizeof(float) * H);
  float4* tab4    = (float4*)alloc(sizeof(float4) * (H + 1) * 64);
  int*    gstart  = (int*)alloc(sizeof(int) * (G + 1));
  float4* vaseg   = (float4*)alloc(sizeof(float4) * N);
  float*  pmax    = (float*)alloc(sizeof(float) * 2 * G * H);
  float*  psum    = (float*)alloc(sizeof(float) * 2 * G * H);
  (void)ws_size; (void)n_in;

  int nbN = (N + 255) / 256;    // 196
  int nbE = (E + 255) / 256;    // 2442

  // zero cnt8 + s1i (contiguous span) in one async memset
  size_t zspan = (size_t)((char*)s1i - (char*)cnt8) + sizeof(int) * 8 * N;
  hipMemsetAsync(cnt8, 0, zspan, stream);

  ka_tables<<<H + 1, H, 0, stream>>>(W1, b1, W2, sortedt, tab4);
  kb_count<<<nbE, 256, 0, stream>>>(ei, E, N, cnt8);
  kc_scan<<<nbN, 256, 0, stream>>>(cnt8, N, cntT, rowptr, bsum);
  kd_finalize<<<nbN, 256, 0, stream>>>(rowptr, bsum, cntT, cnt8, cursor8,
                                       x, dis, ux, batch, gstart, N, E, G, nbN);
  ke_fill<<<nbE, 256, 0, stream>>>(ei, E, N, cursor8, s1i, ux, csr);
  kf_vaseg<<<nbN, 256, 0, stream>>>(s1i, ux, dis, sortedt, vaseg, N);
  kg_agg<<<2 * G, 1024, 0, stream>>>(rowptr, csr, vaseg, tab4, b2, gstart, pmax, psum);
  kh_final<<<G, 256, 0, stream>>>(pmax, psum, gstart, Wout, bout, out);
}

// Round 4
// 231.041 us; speedup vs baseline: 1.4182x; 1.0415x over previous
//
#include <hip/hip_runtime.h>
#include <math.h>
#include <float.h>

#define H 128
#define NCLS 10
#define EPB 2048   // edges per block-slice in count/fill

// ---------------- KA: breakpoint sort + interleaved piecewise tables -------------
// 129 blocks (one per segment) x 128 threads; each block self-computes ranks.
__global__ void ka_tables(const float* __restrict__ W1, const float* __restrict__ b1,
                          const float* __restrict__ W2,
                          float* __restrict__ sortedt, float4* __restrict__ tab4) {
  __shared__ float tw[H], tb[H], tt[H];
  __shared__ int tr[H];
  __shared__ float As[H], Bs[H];
  int t = threadIdx.x;            // 0..127
  int s = blockIdx.x;             // 0..128
  float w = W1[t], b = b1[t];
  tw[t] = w; tb[t] = b;
  tt[t] = (w != 0.0f) ? (-b / w) : INFINITY;
  __syncthreads();
  float tj = tt[t];
  int r = 0;
  for (int i = 0; i < H; ++i) {
    float ti = tt[i];
    r += (ti < tj || (ti == tj && i < t)) ? 1 : 0;
  }
  tr[t] = r;
  if (s == 0) sortedt[r] = tj;
  __syncthreads();
  float A = 0.f, B = 0.f;
  for (int j = 0; j < H; ++j) {
    float wj = tw[j];
    bool active = (wj > 0.f && tr[j] < s) || (wj < 0.f && tr[j] >= s) ||
                  (wj == 0.f && tb[j] > 0.f);
    if (active) {
      float w2 = W2[j * H + t];
      A = fmaf(wj, w2, A);
      B = fmaf(tb[j], w2, B);
    }
  }
  As[t] = A; Bs[t] = B;
  __syncthreads();
  if (t < 64) {
    tab4[s * 64 + t] = make_float4(As[2 * t], As[2 * t + 1], Bs[2 * t], Bs[2 * t + 1]);
  }
}

// ---------------- KB: in-degree count, XCD-range partitioned ---------------------
// block b: node range b%8, edge slice b/8. Atomics stay within one XCD's lines.
__global__ void kb_count(const int* __restrict__ ei, int E, int N,
                         int* __restrict__ cnt, int rangeSize) {
  int g = blockIdx.x & 7;
  int base = (blockIdx.x >> 3) * EPB;
  int lo = g * rangeSize;
  int hi = min(N, lo + rangeSize);
  #pragma unroll
  for (int k = 0; k < EPB / 256; ++k) {
    int e = base + k * 256 + threadIdx.x;
    if (e < E) {
      int dst = ei[E + e];
      if (dst >= lo && dst < hi) atomicAdd(&cnt[dst], 1);
    }
  }
}

// ---------------- KC: per-block scan of cnt --------------------------------------
__global__ void kc_scan(const int* __restrict__ cnt, int N,
                        int* __restrict__ rowptr, int* __restrict__ bsum) {
  __shared__ int arr[256];
  int t = threadIdx.x;
  int idx = blockIdx.x * 256 + t;
  int v = (idx < N) ? cnt[idx] : 0;
  arr[t] = v;
  __syncthreads();
  for (int off = 1; off < 256; off <<= 1) {
    int add = (t >= off) ? arr[t - off] : 0;
    __syncthreads();
    arr[t] += add;
    __syncthreads();
  }
  if (idx < N) rowptr[idx] = arr[t] - v;      // exclusive within block
  if (t == 255) bsum[blockIdx.x] = arr[255];
}

// ---------------- KD: redundant scan2 + rowptr/cursor/dis/ux/gstart --------------
__global__ void kd_finalize(int* __restrict__ rowptr, const int* __restrict__ bsum,
                            const int* __restrict__ cnt, int* __restrict__ cursor,
                            const float* __restrict__ x, float* __restrict__ dis,
                            float* __restrict__ ux, const int* __restrict__ batch,
                            int* __restrict__ gstart, int N, int E, int G,
                            int nScanBlocks) {
  __shared__ int arr[256];
  __shared__ int vown;
  int t = threadIdx.x;
  int v = (t < nScanBlocks) ? bsum[t] : 0;
  arr[t] = v;
  if (t == (int)blockIdx.x) vown = v;
  __syncthreads();
  for (int off = 1; off < 256; off <<= 1) {
    int add = (t >= off) ? arr[t - off] : 0;
    __syncthreads();
    arr[t] += add;
    __syncthreads();
  }
  int boff = arr[blockIdx.x] - vown;          // exclusive block offset
  int idx = blockIdx.x * 256 + t;
  if (idx < N) {
    int r = rowptr[idx] + boff;
    rowptr[idx] = r;
    cursor[idx] = r;
    float d = rsqrtf((float)(cnt[idx] + 1));  // +1 self loop
    dis[idx] = d;
    ux[idx] = d * x[idx];
    int bi = batch[idx];
    if (idx == 0) { gstart[0] = 0; rowptr[N] = E; gstart[G] = N; }
    else if (batch[idx - 1] != bi) gstart[bi] = idx;
  }
}

// ---------------- KE: CSR fill, XCD-range partitioned ----------------------------
__global__ void ke_fill(const int* __restrict__ ei, int E, int N,
                        int* __restrict__ cursor, int* __restrict__ csr,
                        int rangeSize) {
  int g = blockIdx.x & 7;
  int base = (blockIdx.x >> 3) * EPB;
  int lo = g * rangeSize;
  int hi = min(N, lo + rangeSize);
  #pragma unroll
  for (int k = 0; k < EPB / 256; ++k) {
    int e = base + k * 256 + threadIdx.x;
    if (e < E) {
      int dst = ei[E + e];
      if (dst >= lo && dst < hi) {
        int pos = atomicAdd(&cursor[dst], 1);
        csr[pos] = ei[e];
      }
    }
  }
}

// ---------------- KF: s1 gather + vaseg = {d*a, d, seg} --------------------------
__global__ void kf_vaseg(const int* __restrict__ rowptr, const int* __restrict__ csr,
                         const float* __restrict__ ux, const float* __restrict__ dis,
                         const float* __restrict__ sortedt,
                         float4* __restrict__ vaseg, int N) {
  __shared__ float t_s[H];
  if (threadIdx.x < H) t_s[threadIdx.x] = sortedt[threadIdx.x];
  __syncthreads();
  int idx = blockIdx.x * 256 + threadIdx.x;
  if (idx >= N) return;
  int r0 = rowptr[idx], r1 = rowptr[idx + 1];
  float s = ux[idx];                          // self loop
  for (int i = r0; i < r1; ++i) s += ux[csr[i]];
  float d = dis[idx];
  float a = d * s;
  int lo = 0, hi = H;
  while (lo < hi) { int mid = (lo + hi) >> 1; if (t_s[mid] < a) lo = mid + 1; else hi = mid; }
  vaseg[idx] = make_float4(d * a, d, __int_as_float(lo), 0.f);
}

// ---------------- KG: parallel-gather aggregation + partial pool -----------------
__global__ __launch_bounds__(1024)
void kg_agg(const int* __restrict__ rowptr, const int* __restrict__ csr,
            const float4* __restrict__ vaseg, const float4* __restrict__ tab4,
            const float* __restrict__ b2, const int* __restrict__ gstart,
            float* __restrict__ pmax, float* __restrict__ psum) {
  __shared__ float4 stash[16][64];
  __shared__ float lmx[16 * H];
  __shared__ float lsm[16 * H];
  int g = blockIdx.x >> 1, half = blockIdx.x & 1;
  int gs = gstart[g], ge = gstart[g + 1];
  int mid = gs + ((ge - gs) >> 1);
  int s0 = half ? mid : gs;
  int s1e = half ? ge : mid;
  int wave = threadIdx.x >> 6;
  int lane = threadIdx.x & 63;
  int k0 = lane * 2;
  float2 b2v = *(const float2*)&b2[k0];
  float mxa = -FLT_MAX, mxb = -FLT_MAX, sma = 0.f, smb = 0.f;
  for (int d = s0 + wave; d < s1e; d += 16) {
    int r0 = rowptr[d], r1 = rowptr[d + 1];
    float4 pd = vaseg[d];
    int segd = __float_as_int(pd.z);
    float4 T = tab4[segd * 64 + lane];
    float accx = fmaf(pd.x, T.x, pd.y * T.z);      // self-loop term
    float accy = fmaf(pd.x, T.y, pd.y * T.w);
    for (int base = r0; base < r1; base += 64) {
      int m = min(64, r1 - base);
      if (lane < m) {
        int sN = csr[base + lane];
        stash[wave][lane] = vaseg[sN];             // parallel gather
      }
      __builtin_amdgcn_wave_barrier();
      __threadfence_block();                       // order LDS write -> read (wave-local)
      for (int j = 0; j < m; ++j) {
        float4 ps = stash[wave][j];                // broadcast read
        int seg = __float_as_int(ps.z);
        float4 Tj = tab4[seg * 64 + lane];
        accx = fmaf(ps.x, Tj.x, fmaf(ps.y, Tj.z, accx));
        accy = fmaf(ps.x, Tj.y, fmaf(ps.y, Tj.w, accy));
      }
      __builtin_amdgcn_wave_barrier();
    }
    float dd = pd.y;
    float ha = fmaxf(fmaf(dd, accx, b2v.x), 0.f);
    float hb = fmaxf(fmaf(dd, accy, b2v.y), 0.f);
    mxa = fmaxf(mxa, ha); mxb = fmaxf(mxb, hb);
    sma += ha; smb += hb;
  }
  lmx[wave * H + k0] = mxa; lmx[wave * H + k0 + 1] = mxb;
  lsm[wave * H + k0] = sma; lsm[wave * H + k0 + 1] = smb;
  __syncthreads();
  int t = threadIdx.x;
  if (t < H) {
    float m = -FLT_MAX, sm = 0.f;
    #pragma unroll
    for (int w = 0; w < 16; ++w) { m = fmaxf(m, lmx[w * H + t]); sm += lsm[w * H + t]; }
    pmax[(size_t)blockIdx.x * H + t] = m;
    psum[(size_t)blockIdx.x * H + t] = sm;
  }
}

// ---------------- KH: combine halves + classifier + softmax ----------------------
__global__ void kh_final(const float* __restrict__ pmax, const float* __restrict__ psum,
                         const int* __restrict__ gstart,
                         const float* __restrict__ Wout, const float* __restrict__ bout,
                         float* __restrict__ out) {
  int g = blockIdx.x;
  int t = threadIdx.x;
  __shared__ float pooled[2 * H];
  __shared__ float logits[NCLS];
  if (t < H) {
    float m = fmaxf(pmax[(size_t)(2 * g) * H + t], pmax[(size_t)(2 * g + 1) * H + t]);
    float sm = psum[(size_t)(2 * g) * H + t] + psum[(size_t)(2 * g + 1) * H + t];
    float cnt = (float)(gstart[g + 1] - gstart[g]);
    pooled[t] = m;
    pooled[H + t] = sm / fmaxf(cnt, 1.0f);
  }
  __syncthreads();
  if (t < NCLS) {
    float acc = bout[t];
    for (int j = 0; j < 2 * H; ++j) acc = fmaf(pooled[j], Wout[j * NCLS + t], acc);
    logits[t] = acc;
  }
  __syncthreads();
  if (t == 0) {
    float m = logits[0];
    for (int c = 1; c < NCLS; ++c) m = fmaxf(m, logits[c]);
    float ssum = 0.f;
    float ex[NCLS];
    for (int c = 0; c < NCLS; ++c) { ex[c] = expf(logits[c] - m); ssum += ex[c]; }
    float inv = 1.0f / ssum;
    for (int c = 0; c < NCLS; ++c) out[g * NCLS + c] = ex[c] * inv;
  }
}

extern "C" void kernel_launch(void* const* d_in, const int* in_sizes, int n_in,
                              void* d_out, int out_size, void* d_ws, size_t ws_size,
                              hipStream_t stream) {
  const float* x    = (const float*)d_in[0];
  const int*   ei   = (const int*)d_in[1];
  const int*   batch= (const int*)d_in[2];
  const float* W1   = (const float*)d_in[3];
  const float* b1   = (const float*)d_in[4];
  const float* W2   = (const float*)d_in[5];
  const float* b2   = (const float*)d_in[6];
  const float* Wout = (const float*)d_in[7];
  const float* bout = (const float*)d_in[8];
  float* out = (float*)d_out;

  int N = in_sizes[0];          // 50000
  int E = in_sizes[1] / 2;      // 625000
  int G = out_size / NCLS;      // 256

  char* ws = (char*)d_ws;
  size_t off = 0;
  auto alloc = [&](size_t bytes) {
    char* p = ws + off;
    off += (bytes + 255) & ~(size_t)255;
    return p;
  };
  int*    cnt     = (int*)alloc(sizeof(int) * N);
  int*    rowptr  = (int*)alloc(sizeof(int) * (N + 1));
  int*    cursor  = (int*)alloc(sizeof(int) * N);
  int*    csr     = (int*)alloc(sizeof(int) * E);
  int*    bsum    = (int*)alloc(sizeof(int) * 256);
  float*  dis     = (float*)alloc(sizeof(float) * N);
  float*  ux      = (float*)alloc(sizeof(float) * N);
  float*  sortedt = (float*)alloc(sizeof(float) * H);
  float4* tab4    = (float4*)alloc(sizeof(float4) * (H + 1) * 64);
  int*    gstart  = (int*)alloc(sizeof(int) * (G + 1));
  float4* vaseg   = (float4*)alloc(sizeof(float4) * N);
  float*  pmax    = (float*)alloc(sizeof(float) * 2 * G * H);
  float*  psum    = (float*)alloc(sizeof(float) * 2 * G * H);
  (void)ws_size; (void)n_in;

  int nbN = (N + 255) / 256;          // 196
  int nbS = (E + EPB - 1) / EPB;      // 306 edge slices
  int rangeSize = (N + 7) / 8;        // 6250 nodes per XCD range

  hipMemsetAsync(cnt, 0, sizeof(int) * N, stream);

  ka_tables<<<H + 1, H, 0, stream>>>(W1, b1, W2, sortedt, tab4);
  kb_count<<<nbS * 8, 256, 0, stream>>>(ei, E, N, cnt, rangeSize);
  kc_scan<<<nbN, 256, 0, stream>>>(cnt, N, rowptr, bsum);
  kd_finalize<<<nbN, 256, 0, stream>>>(rowptr, bsum, cnt, cursor,
                                       x, dis, ux, batch, gstart, N, E, G, nbN);
  ke_fill<<<nbS * 8, 256, 0, stream>>>(ei, E, N, cursor, csr, rangeSize);
  kf_vaseg<<<nbN, 256, 0, stream>>>(rowptr, csr, ux, dis, sortedt, vaseg, N);
  kg_agg<<<2 * G, 1024, 0, stream>>>(rowptr, csr, vaseg, tab4, b2, gstart, pmax, psum);
  kh_final<<<G, 256, 0, stream>>>(pmax, psum, gstart, Wout, bout, out);
}